// Round 4
// baseline (612.608 us; speedup 1.0000x reference)
//
#include <hip/hip_runtime.h>

// EGNN fused layer, MI355X gfx950 — v5 (launch-overhead + occupancy round).
// out[0 : 50000*64)          = h + segment_sum(node messages, dst)
// out[50000*64 : +50000*3)   = x + segment_sum(coord updates, dst)
//
// v4 post-mortem: sort cut WRITE 275->36MB but main only -12% (atomic theory
// mostly wrong); 7 extra launches cost ~160us (~10us/launch harness overhead).
// Occupancy pinned ~21% every round: total VGPR+AGPR = 128+64 = 192 -> hard
// 2 blocks/CU register cap (rocprof VGPR_Count shows arch regs only).
// Changes vs v4:
//  - ONE prep kernel (fold + init_out + hist + scan + scatter) with a manual
//    device-scope grid barrier (512 resident light blocks, atomic arrive +
//    spin + threadfence).  10 dispatches -> memset + prep + main.
//  - main: __launch_bounds__(256,3) (<=170 regs -> 3 blocks/CU) and GEMM1
//    split into N-pass then C-pass (peak live acc 64 -> 32 VGPRs; A-frags
//    re-read from LDS).
//  - barriers 5 -> 4: src/dst loaded directly from sorted arrays (L2-hot)
//    in staging; src_l/dst_l LDS written same phase, read post-GEMM only.
//  - grid 768 = 3 blocks/CU x 256 CU.

#define NN 50000
#define NE 800000
#define NDIM 64
#define HDIM 128
#define NTILES (NE / 64)      // 12500, exact
#define MSTRIDE 168           // m_input LDS row stride (ushorts): 160 + 8 pad
#define HSTRIDE 136           // hidden LDS row stride: 128 + 8 pad
#define MLSTRIDE 65           // f32 m-tile stride (floats)
#define NH (NN * NDIM)        // 3,200,000
#define NX (NN * 3)           // 150,000

// workspace layout
#define WS_WN1P 0             // [160][128] floats
#define WS_WC1P 20480         // [160][128]
#define WS_BN1P 40960         // [128]
#define WS_BC1P 41088         // [128]
#define WS_WEIGHTS_FLOATS 65536
#define NCNT 50176            // 196*256
// int offsets from (int*)ws:
#define IOFF_CNT    WS_WEIGHTS_FLOATS
#define IOFF_CUR    (IOFF_CNT + NCNT)
#define IOFF_SYNC   (IOFF_CUR + NCNT)          // 64 ints (4 counters, spaced 16)
#define IOFF_BLK    (IOFF_SYNC + 64)           // 256 ints (196 used)
#define IOFF_SRCS   (IOFF_BLK + 256)
#define IOFF_DSTS   (IOFF_SRCS + NE)
#define IOFF_DISTS  (IOFF_DSTS + NE)
#define WS_TOTAL_BYTES ((size_t)(IOFF_DISTS + NE) * 4)
#define MEMSET_OFF_BYTES ((size_t)IOFF_CNT * 4)
#define MEMSET_BYTES ((size_t)(2 * NCNT + 64 + 256) * 4)   // cnt+cur+sync+blk

#define PREP_NB 512           // prep grid; light kernel -> all resident

typedef __bf16 bf16x8 __attribute__((ext_vector_type(8)));
typedef float f32x4 __attribute__((ext_vector_type(4)));
typedef unsigned short ushort8 __attribute__((ext_vector_type(8)));
typedef unsigned short ushort4v __attribute__((ext_vector_type(4)));

__device__ __forceinline__ unsigned short f2bf(float f) {
    union { __bf16 b; unsigned short u; } c;
    c.b = (__bf16)f;
    return c.u;
}
__device__ __forceinline__ float silu(float v) {
    return __fdividef(v, 1.0f + __expf(-v));
}
__device__ __forceinline__ void bar_lds() {   // lgkm-only barrier (atomics stay in flight)
    asm volatile("s_waitcnt lgkmcnt(0)" ::: "memory");
    __builtin_amdgcn_s_barrier();
}
__device__ __forceinline__ bf16x8 ld_frag(const unsigned short* p) {
    union { ushort8 u; bf16x8 v; } c;
    c.u = *(const ushort8*)p;
    return c.v;
}
__device__ __forceinline__ bf16x8 mk_frag(const unsigned short* u) {
    union { ushort8 uu; bf16x8 v; } c;
#pragma unroll
    for (int j = 0; j < 8; ++j) c.uu[j] = u[j];
    return c.v;
}

// ---------------- fused prep kernel (fold + init + sort) ----------------

__device__ __forceinline__ void gsync(int* sc) {
    __syncthreads();
    if (threadIdx.x == 0) {
        __threadfence();                       // release: make block writes visible
        atomicAdd(sc, 1);
        while (__hip_atomic_load(sc, __ATOMIC_RELAXED, __HIP_MEMORY_SCOPE_AGENT) < PREP_NB)
            __builtin_amdgcn_s_sleep(2);
        __threadfence();                       // acquire
    }
    __syncthreads();
}

__global__ __launch_bounds__(256) void prep(
    const float* __restrict__ h, const float* __restrict__ x,
    const int* __restrict__ src0, const int* __restrict__ dst0,
    const float* __restrict__ dist0,
    const float* __restrict__ We2, const float* __restrict__ be2,
    const float* __restrict__ Wn1, const float* __restrict__ bn1,
    const float* __restrict__ Wc1, const float* __restrict__ bc1,
    float* __restrict__ out, int* __restrict__ wsi, int do_sort) {

    __shared__ int sh[256];
    const int gtid = blockIdx.x * 256 + threadIdx.x;
    const int G = PREP_NB * 256;

    float* wsf = (float*)wsi;
    int* cnt  = wsi + IOFF_CNT;
    int* cur  = wsi + IOFF_CUR;
    int* sync = wsi + IOFF_SYNC;
    int* blk  = wsi + IOFF_BLK;

    // ---- phase A: fold weights + init out (cnt/cur/sync zeroed by memset) ----
    for (int i = gtid; i < 41216; i += G) {
        if (i < 40960) {
            const int path = i / 20480;
            const int rem = i - path * 20480;
            const int r = rem >> 7, col = rem & 127;
            const float* W = path ? Wc1 : Wn1;
            float* Wp = wsf + (path ? WS_WC1P : WS_WN1P);
            if (r < 128) {
                Wp[r * 128 + col] = W[r * 128 + col];
            } else {
                const int j = r - 128;
                float s = 0.0f;
#pragma unroll
                for (int n = 0; n < 32; ++n)
                    s += We2[j * 32 + n] * W[(128 + n) * 128 + col];
                Wp[r * 128 + col] = s;
            }
        } else {
            const int j = i - 40960;
            const int path = j >> 7, col = j & 127;
            const float* W = path ? Wc1 : Wn1;
            const float* bb = path ? bc1 : bn1;
            float s = bb[col];
#pragma unroll
            for (int n = 0; n < 32; ++n)
                s += be2[n] * W[(128 + n) * 128 + col];
            wsf[(path ? WS_BC1P : WS_BN1P) + col] = s;
        }
    }
    for (int i = gtid; i < NH + NX; i += G)
        out[i] = (i < NH) ? h[i] : x[i - NH];

    if (!do_sort) return;

    gsync(&sync[0]);

    // ---- phase B: histogram of dst ----
    for (int e = gtid; e < NE; e += G)
        atomicAdd(&cnt[dst0[e]], 1);

    gsync(&sync[16]);

    // ---- phase C1: per-256-group exclusive scan (196 groups) ----
    if (blockIdx.x < 196) {
        const int t = threadIdx.x;
        const int i = blockIdx.x * 256 + t;
        const int v = cnt[i];
        sh[t] = v;
        __syncthreads();
#pragma unroll
        for (int d = 1; d < 256; d <<= 1) {
            const int o = (t >= d) ? sh[t - d] : 0;
            __syncthreads();
            sh[t] += o;
            __syncthreads();
        }
        cnt[i] = sh[t] - v;
        if (t == 255) blk[blockIdx.x] = sh[t];
    }

    gsync(&sync[32]);

    // ---- phase C2: block 0 scans the 196 group sums ----
    if (blockIdx.x == 0) {
        const int t = threadIdx.x;
        const int v = (t < 196) ? blk[t] : 0;
        sh[t] = v;
        __syncthreads();
#pragma unroll
        for (int d = 1; d < 256; d <<= 1) {
            const int o = (t >= d) ? sh[t - d] : 0;
            __syncthreads();
            sh[t] += o;
            __syncthreads();
        }
        if (t < 196) blk[t] = sh[t] - v;
    }

    gsync(&sync[48]);

    // ---- phase D: scatter edges to sorted order (group offset fused) ----
    int* srcs = wsi + IOFF_SRCS;
    int* dsts = wsi + IOFF_DSTS;
    float* dists = (float*)(wsi + IOFF_DISTS);
    for (int e = gtid; e < NE; e += G) {
        const int d = dst0[e];
        const int pos = cnt[d] + blk[d >> 8] + atomicAdd(&cur[d], 1);
        srcs[pos] = src0[e];
        dsts[pos] = d;
        dists[pos] = dist0[e];
    }
}

// ---------------- main fused kernel ----------------

__global__ __launch_bounds__(256, 3) void egnn_edges(
    const float* __restrict__ h, const float* __restrict__ x,
    const int* __restrict__ srcg, const int* __restrict__ dstg,
    const float* __restrict__ dist,
    const float* __restrict__ We1, const float* __restrict__ be1,
    const float* __restrict__ Wn2, const float* __restrict__ bn2,
    const float* __restrict__ Wc2,
    const float* __restrict__ wsW,
    float* __restrict__ outh, float* __restrict__ outx) {

    __shared__ __align__(16) unsigned short mlds[64 * MSTRIDE];  // bf16 m_input; f32 m-tile later
    __shared__ __align__(16) unsigned short hl[64 * HSTRIDE];    // hidden tile bf16
    __shared__ int src_l[64];
    __shared__ int dst_l[64];
    __shared__ float we1_l[32], be1_l[32];
    __shared__ float part_l[256];
    __shared__ float cx_l[64], cy_l[64], cz_l[64];

    const int tid  = threadIdx.x;
    const int w    = tid >> 6;        // wave 0..3
    const int lane = tid & 63;
    const int l15  = lane & 15;
    const int quad = lane >> 4;

    const float* Wn1p = wsW + WS_WN1P;
    const float* Wc1p = wsW + WS_WC1P;
    const float* bn1p = wsW + WS_BN1P;
    const float* bc1p = wsW + WS_BC1P;

    if (tid < 32) { we1_l[tid] = We1[tid]; be1_l[tid] = be1[tid]; }

    // ---- one-time: B-fragments to registers (from folded weights) ----
    bf16x8 wn1f[5][2], wc1f[5][2];
#pragma unroll
    for (int kc = 0; kc < 5; ++kc) {
#pragma unroll
        for (int nt = 0; nt < 2; ++nt) {
            unsigned short un[8], uc[8];
            const int n = w * 32 + nt * 16 + l15;
#pragma unroll
            for (int j = 0; j < 8; ++j) {
                const int k = kc * 32 + quad * 8 + j;
                un[j] = f2bf(Wn1p[k * HDIM + n]);
                uc[j] = f2bf(Wc1p[k * HDIM + n]);
            }
            wn1f[kc][nt] = mk_frag(un);
            wc1f[kc][nt] = mk_frag(uc);
        }
    }
    bf16x8 wn2f[4];
#pragma unroll
    for (int kc = 0; kc < 4; ++kc) {
        unsigned short u[8];
        const int n = w * 16 + l15;
#pragma unroll
        for (int j = 0; j < 8; ++j) {
            const int k = kc * 32 + quad * 8 + j;
            u[j] = f2bf(Wn2[k * NDIM + n]);
        }
        wn2f[kc] = mk_frag(u);
    }
    const float biasN0 = bn1p[w * 32 + l15];
    const float biasN1 = bn1p[w * 32 + 16 + l15];
    const float biasC0 = bc1p[w * 32 + l15];
    const float biasC1 = bc1p[w * 32 + 16 + l15];
    const float bias2v = bn2[w * 16 + l15];
    const float wcA = Wc2[w * 32 + l15];
    const float wcB = Wc2[w * 32 + 16 + l15];

    for (int tile = blockIdx.x; tile < NTILES; tile += gridDim.x) {
        const int e0 = tile * 64;
        bar_lds();   // (1) LDS of previous tile fully consumed

        // ---- staging: m_input = [h[src] | h[dst] | s] bf16; src/dst straight
        //      from sorted arrays (L2-hot); src_l/dst_l for post-GEMM phases ----
        if (tid < 64) { src_l[tid] = srcg[e0 + tid]; dst_l[tid] = dstg[e0 + tid]; }
        {
            const int c4 = tid & 15, sub = tid >> 4;
#pragma unroll
            for (int it = 0; it < 4; ++it) {
                const int el = sub + it * 16;
                const int sn = srcg[e0 + el];
                const int dn = dstg[e0 + el];
                const float4 hs = *(const float4*)(h + (size_t)sn * NDIM + c4 * 4);
                const float4 hd = *(const float4*)(h + (size_t)dn * NDIM + c4 * 4);
                ushort4v us = { f2bf(hs.x), f2bf(hs.y), f2bf(hs.z), f2bf(hs.w) };
                ushort4v ud = { f2bf(hd.x), f2bf(hd.y), f2bf(hd.z), f2bf(hd.w) };
                *(ushort4v*)&mlds[el * MSTRIDE + c4 * 4] = us;
                *(ushort4v*)&mlds[el * MSTRIDE + 64 + c4 * 4] = ud;
            }
        }
        {
            const int el = tid >> 2, j0 = (tid & 3) * 8;
            const float dv = dist[e0 + el];
            ushort8 u;
#pragma unroll
            for (int j = 0; j < 8; ++j)
                u[j] = f2bf(silu(dv * we1_l[j0 + j] + be1_l[j0 + j]));
            *(ushort8*)&mlds[el * MSTRIDE + 128 + j0] = u;
        }
        bar_lds();   // (2) m_input ready

        // ---- GEMM1 pass N: [64x160] @ Wn1' ; silu -> hl ----
        {
            f32x4 accN[4][2];
#pragma unroll
            for (int mt = 0; mt < 4; ++mt) {
                accN[mt][0] = (f32x4){biasN0, biasN0, biasN0, biasN0};
                accN[mt][1] = (f32x4){biasN1, biasN1, biasN1, biasN1};
            }
#pragma unroll
            for (int kc = 0; kc < 5; ++kc) {
#pragma unroll
                for (int mt = 0; mt < 4; ++mt) {
                    bf16x8 af = ld_frag(&mlds[(mt * 16 + l15) * MSTRIDE + kc * 32 + quad * 8]);
                    accN[mt][0] = __builtin_amdgcn_mfma_f32_16x16x32_bf16(af, wn1f[kc][0], accN[mt][0], 0, 0, 0);
                    accN[mt][1] = __builtin_amdgcn_mfma_f32_16x16x32_bf16(af, wn1f[kc][1], accN[mt][1], 0, 0, 0);
                }
            }
#pragma unroll
            for (int mt = 0; mt < 4; ++mt)
#pragma unroll
                for (int nt = 0; nt < 2; ++nt)
#pragma unroll
                    for (int r = 0; r < 4; ++r)
                        hl[(mt * 16 + quad * 4 + r) * HSTRIDE + w * 32 + nt * 16 + l15] =
                            f2bf(silu(accN[mt][nt][r]));
        }

        // ---- GEMM1 pass C: [64x160] @ Wc1' ; silu*Wc2 + butterfly reduce ----
        {
            f32x4 accC[4][2];
#pragma unroll
            for (int mt = 0; mt < 4; ++mt) {
                accC[mt][0] = (f32x4){biasC0, biasC0, biasC0, biasC0};
                accC[mt][1] = (f32x4){biasC1, biasC1, biasC1, biasC1};
            }
#pragma unroll
            for (int kc = 0; kc < 5; ++kc) {
#pragma unroll
                for (int mt = 0; mt < 4; ++mt) {
                    bf16x8 af = ld_frag(&mlds[(mt * 16 + l15) * MSTRIDE + kc * 32 + quad * 8]);
                    accC[mt][0] = __builtin_amdgcn_mfma_f32_16x16x32_bf16(af, wc1f[kc][0], accC[mt][0], 0, 0, 0);
                    accC[mt][1] = __builtin_amdgcn_mfma_f32_16x16x32_bf16(af, wc1f[kc][1], accC[mt][1], 0, 0, 0);
                }
            }
            float p[16];
#pragma unroll
            for (int mt = 0; mt < 4; ++mt)
#pragma unroll
                for (int r = 0; r < 4; ++r)
                    p[mt * 4 + r] = silu(accC[mt][0][r]) * wcA + silu(accC[mt][1][r]) * wcB;

            float q8[8];
#pragma unroll
            for (int i = 0; i < 8; ++i) {
                const float send = (l15 & 8) ? p[i] : p[i + 8];
                const float recv = __shfl_xor(send, 8, 64);
                q8[i] = ((l15 & 8) ? p[i + 8] : p[i]) + recv;
            }
            float q4[4];
#pragma unroll
            for (int i = 0; i < 4; ++i) {
                const float send = (l15 & 4) ? q8[i] : q8[i + 4];
                const float recv = __shfl_xor(send, 4, 64);
                q4[i] = ((l15 & 4) ? q8[i + 4] : q8[i]) + recv;
            }
            float q2[2];
#pragma unroll
            for (int i = 0; i < 2; ++i) {
                const float send = (l15 & 2) ? q4[i] : q4[i + 2];
                const float recv = __shfl_xor(send, 2, 64);
                q2[i] = ((l15 & 2) ? q4[i + 2] : q4[i]) + recv;
            }
            {
                const float send = (l15 & 1) ? q2[0] : q2[1];
                const float recv = __shfl_xor(send, 1, 64);
                const float tot = ((l15 & 1) ? q2[1] : q2[0]) + recv;
                const int edge = (l15 >> 2) * 16 + quad * 4 + (l15 & 3);
                part_l[w * 64 + edge] = tot;
            }
        }
        bar_lds();   // (3) hl + part_l ready

        // ---- GEMM2 node: [64x128] @ Wn2 -> m [64x64] -> f32 LDS tile ----
        {
            f32x4 acc2[4];
#pragma unroll
            for (int mt = 0; mt < 4; ++mt) acc2[mt] = (f32x4){bias2v, bias2v, bias2v, bias2v};
#pragma unroll
            for (int kc = 0; kc < 4; ++kc) {
#pragma unroll
                for (int mt = 0; mt < 4; ++mt) {
                    bf16x8 a2 = ld_frag(&hl[(mt * 16 + l15) * HSTRIDE + kc * 32 + quad * 8]);
                    acc2[mt] = __builtin_amdgcn_mfma_f32_16x16x32_bf16(a2, wn2f[kc], acc2[mt], 0, 0, 0);
                }
            }
            float* ml = (float*)mlds;   // reuse; bf16 reads all done pre-(3)
#pragma unroll
            for (int mt = 0; mt < 4; ++mt)
#pragma unroll
                for (int r = 0; r < 4; ++r)
                    ml[(mt * 16 + quad * 4 + r) * MLSTRIDE + w * 16 + l15] = acc2[mt][r];
        }

        // ---- coord per-edge contributions -> LDS ----
        if (tid < 64) {
            const float cw = part_l[tid] + part_l[64 + tid] + part_l[128 + tid] + part_l[192 + tid];
            const int sn = src_l[tid], dn = dst_l[tid];
            const float dx = x[sn * 3 + 0] - x[dn * 3 + 0];
            const float dy = x[sn * 3 + 1] - x[dn * 3 + 1];
            const float dz = x[sn * 3 + 2] - x[dn * 3 + 2];
            float len = sqrtf(dx * dx + dy * dy + dz * dz);
            len = fmaxf(len, 1e-8f);
            const float f = cw / len;
            cx_l[tid] = f * dx; cy_l[tid] = f * dy; cz_l[tid] = f * dz;
        }
        bar_lds();   // (4) ml + cx/cy/cz ready

        // ---- segmented reduction over sorted-dst runs (coalesced atomics) ----
        {
            const int c = lane;
            const int r0 = w * 16;
            float acc = ((const float*)mlds)[r0 * MLSTRIDE + c];
            int d = dst_l[r0];
#pragma unroll
            for (int r = r0 + 1; r < r0 + 16; ++r) {
                const int dn = dst_l[r];
                if (dn != d) {
                    atomicAdd(outh + (size_t)d * NDIM + c, acc);
                    acc = 0.0f;
                    d = dn;
                }
                acc += ((const float*)mlds)[r * MLSTRIDE + c];
            }
            atomicAdd(outh + (size_t)d * NDIM + c, acc);
        }

        // ---- coord: run-start lanes combine their run ----
        if (tid < 64) {
            const int d = dst_l[tid];
            if (tid == 0 || dst_l[tid - 1] != d) {
                float sx = 0.0f, sy = 0.0f, sz = 0.0f;
                int r = tid;
                do {
                    sx += cx_l[r]; sy += cy_l[r]; sz += cz_l[r];
                    ++r;
                } while (r < 64 && dst_l[r] == d);
                atomicAdd(outx + (size_t)d * 3 + 0, sx);
                atomicAdd(outx + (size_t)d * 3 + 1, sy);
                atomicAdd(outx + (size_t)d * 3 + 2, sz);
            }
        }
    }
}

extern "C" void kernel_launch(void* const* d_in, const int* in_sizes, int n_in,
                              void* d_out, int out_size, void* d_ws, size_t ws_size,
                              hipStream_t stream) {
    const float* h    = (const float*)d_in[0];
    const float* x    = (const float*)d_in[1];
    const int*   ei   = (const int*)d_in[2];     // int32, [2, NE]
    const float* dist = (const float*)d_in[3];
    const float* We1  = (const float*)d_in[4];
    const float* be1  = (const float*)d_in[5];
    const float* We2  = (const float*)d_in[6];
    const float* be2  = (const float*)d_in[7];
    const float* Wn1  = (const float*)d_in[8];
    const float* bn1  = (const float*)d_in[9];
    const float* Wn2  = (const float*)d_in[10];
    const float* bn2  = (const float*)d_in[11];
    const float* Wc1  = (const float*)d_in[12];
    const float* bc1  = (const float*)d_in[13];
    const float* Wc2  = (const float*)d_in[14];

    float* outh = (float*)d_out;
    float* outx = outh + (size_t)NH;
    int*   wsi  = (int*)d_ws;

    const int do_sort = (ws_size >= WS_TOTAL_BYTES) ? 1 : 0;
    if (do_sort)
        hipMemsetAsync((char*)d_ws + MEMSET_OFF_BYTES, 0, MEMSET_BYTES, stream);

    prep<<<PREP_NB, 256, 0, stream>>>(h, x, ei, ei + NE, dist,
                                      We2, be2, Wn1, bn1, Wc1, bc1,
                                      (float*)d_out, wsi, do_sort);

    const int* es = ei;
    const int* ed = ei + NE;
    const float* edist = dist;
    if (do_sort) {
        es = wsi + IOFF_SRCS;
        ed = wsi + IOFF_DSTS;
        edist = (const float*)(wsi + IOFF_DISTS);
    }

    egnn_edges<<<768, 256, 0, stream>>>(h, x, es, ed, edist,
                                        We1, be1, Wn2, bn2, Wc2,
                                        (const float*)d_ws,
                                        outh, outx);
}

// Round 5
// 444.702 us; speedup vs baseline: 1.3776x; 1.3776x over previous
//
#include <hip/hip_runtime.h>

// EGNN fused layer, MI355X gfx950 — v6 (LDS/VALU-cut + 2-launch round).
// out[0 : 50000*64)          = h + segment_sum(node messages, dst)
// out[50000*64 : +50000*3)   = x + segment_sum(coord updates, dst)
//
// v5 post-mortem: occupancy +50% -> time flat (3rd falsified single-pipe
// theory).  Fitting model: time ~ VALU-busy + LDS-busy serialized by
// dependency chains.  Sort = net-negative (prep >= its -42us benefit);
// ~35us/launch harness overhead -> minimize launches.
// Changes vs v5:
//  - NO sort, NO grid-sync prep: one prep kernel (fold weights + init out),
//    one main kernel.  2 launches total.
//  - pi-permuted hidden dim (slot w*32+2*l15+nt holds dim w*32+nt*16+l15;
//    Wn2 rows permuted to match): hl round trip 32 ds_write_u16 -> 16
//    ds_write_b32, 32 cvt -> 16 packed.
//  - GEMM1 N+C merged again (20 ds_read_b128, not 40).
//  - 3 barriers/tile (was 4-5), all lgkm-only.
//  - T14: next-tile src/dst/dist + h float4 gathers prefetched into regs
//    during current tile's compute; epilogue x[] prefetched at stage time.
//  - direct per-edge atomic epilogue (v3 style; no ml/cx round trips).

#define NN 50000
#define NE 800000
#define NDIM 64
#define HDIM 128
#define NTILES (NE / 64)      // 12500, exact
#define MSTRIDE 168           // m_input LDS row stride (ushorts): 160 + 8 pad
#define HSTRIDE 136           // hidden LDS row stride (ushorts): 128 + 8 pad
#define NH (NN * NDIM)        // 3,200,000
#define NX (NN * 3)           // 150,000

// workspace layout (floats) — folded weights only
#define WS_WN1P 0             // [160][128]
#define WS_WC1P 20480         // [160][128]
#define WS_BN1P 40960         // [128]
#define WS_BC1P 41088         // [128]

typedef __bf16 bf16x8 __attribute__((ext_vector_type(8)));
typedef float f32x4 __attribute__((ext_vector_type(4)));
typedef unsigned short ushort8 __attribute__((ext_vector_type(8)));
typedef unsigned short ushort4v __attribute__((ext_vector_type(4)));

__device__ __forceinline__ unsigned short f2bf(float f) {
    union { __bf16 b; unsigned short u; } c;
    c.b = (__bf16)f;            // HW v_cvt (RNE); compiler pairs into cvt_pk
    return c.u;
}
__device__ __forceinline__ float silu(float v) {
    return __fdividef(v, 1.0f + __expf(-v));
}
// lgkm-only barrier: all cross-thread deps flow through LDS; atomics and
// prefetch loads stay in flight across it.
__device__ __forceinline__ void bar_lds() {
    asm volatile("s_waitcnt lgkmcnt(0)" ::: "memory");
    __builtin_amdgcn_s_barrier();
}
__device__ __forceinline__ bf16x8 ld_frag(const unsigned short* p) {
    union { ushort8 u; bf16x8 v; } c;
    c.u = *(const ushort8*)p;
    return c.v;
}
__device__ __forceinline__ bf16x8 mk_frag(const unsigned short* u) {
    union { ushort8 uu; bf16x8 v; } c;
#pragma unroll
    for (int j = 0; j < 8; ++j) c.uu[j] = u[j];
    return c.v;
}

// ---- prep: fold We2/be2 into GEMM1 weights + init out.  One launch. ----
__global__ __launch_bounds__(256) void prep(
    const float* __restrict__ h, const float* __restrict__ x,
    const float* __restrict__ We2, const float* __restrict__ be2,
    const float* __restrict__ Wn1, const float* __restrict__ bn1,
    const float* __restrict__ Wc1, const float* __restrict__ bc1,
    float* __restrict__ out, float* __restrict__ wsf) {
    const int gtid = blockIdx.x * 256 + threadIdx.x;
    const int G = gridDim.x * 256;
    if (gtid < 41216) {
        if (gtid < 40960) {
            const int path = gtid / 20480;
            const int rem = gtid - path * 20480;
            const int r = rem >> 7, col = rem & 127;
            const float* W = path ? Wc1 : Wn1;
            float* Wp = wsf + (path ? WS_WC1P : WS_WN1P);
            if (r < 128) {
                Wp[r * 128 + col] = W[r * 128 + col];
            } else {
                const int j = r - 128;          // s-dim index 0..31
                float s = 0.0f;
#pragma unroll
                for (int n = 0; n < 32; ++n)
                    s += We2[j * 32 + n] * W[(128 + n) * 128 + col];
                Wp[r * 128 + col] = s;
            }
        } else {
            const int j = gtid - 40960;         // 0..255
            const int path = j >> 7, col = j & 127;
            const float* W = path ? Wc1 : Wn1;
            const float* bb = path ? bc1 : bn1;
            float s = bb[col];
#pragma unroll
            for (int n = 0; n < 32; ++n)
                s += be2[n] * W[(128 + n) * 128 + col];
            wsf[(path ? WS_BC1P : WS_BN1P) + col] = s;
        }
    }
    for (int i = gtid; i < NH + NX; i += G)
        out[i] = (i < NH) ? h[i] : x[i - NH];
}

// ---- main fused kernel ----
__global__ __launch_bounds__(256) void egnn_edges(
    const float* __restrict__ h, const float* __restrict__ x,
    const int* __restrict__ srcg, const int* __restrict__ dstg,
    const float* __restrict__ dist,
    const float* __restrict__ We1, const float* __restrict__ be1,
    const float* __restrict__ Wn2, const float* __restrict__ bn2,
    const float* __restrict__ Wc2,
    const float* __restrict__ wsW,
    float* __restrict__ outh, float* __restrict__ outx) {

    __shared__ __align__(16) unsigned short mlds[64 * MSTRIDE];  // m_input tile bf16
    __shared__ __align__(16) unsigned short hl[64 * HSTRIDE];    // hidden tile bf16 (pi-permuted cols)
    __shared__ int src_l[64];
    __shared__ int dst_l[64];
    __shared__ float we1_l[32], be1_l[32];
    __shared__ float part_l[256];

    const int tid  = threadIdx.x;
    const int w    = tid >> 6;        // wave 0..3
    const int lane = tid & 63;
    const int l15  = lane & 15;
    const int quad = lane >> 4;
    const int c4   = tid & 15, sub = tid >> 4;   // staging geometry

    const float* Wn1p = wsW + WS_WN1P;
    const float* Wc1p = wsW + WS_WC1P;
    const float* bn1p = wsW + WS_BN1P;
    const float* bc1p = wsW + WS_BC1P;

    if (tid < 32) { we1_l[tid] = We1[tid]; be1_l[tid] = be1[tid]; }

    // ---- one-time: B-fragments to registers ----
    bf16x8 wn1f[5][2], wc1f[5][2];
#pragma unroll
    for (int kc = 0; kc < 5; ++kc) {
#pragma unroll
        for (int nt = 0; nt < 2; ++nt) {
            unsigned short un[8], uc[8];
            const int n = w * 32 + nt * 16 + l15;
#pragma unroll
            for (int j = 0; j < 8; ++j) {
                const int k = kc * 32 + quad * 8 + j;
                un[j] = f2bf(Wn1p[k * HDIM + n]);
                uc[j] = f2bf(Wc1p[k * HDIM + n]);
            }
            wn1f[kc][nt] = mk_frag(un);
            wc1f[kc][nt] = mk_frag(uc);
        }
    }
    // GEMM2 B-frags with pi-permuted k:  slot k holds hidden dim
    // D(k) = (k&~31) + ((k&1)<<4) + ((k&31)>>1)   (bijective per 32-block)
    bf16x8 wn2f[4];
#pragma unroll
    for (int kc = 0; kc < 4; ++kc) {
        unsigned short u[8];
        const int n = w * 16 + l15;
#pragma unroll
        for (int j = 0; j < 8; ++j) {
            const int k = kc * 32 + quad * 8 + j;
            const int D = (k & ~31) + ((k & 1) << 4) + ((k & 31) >> 1);
            u[j] = f2bf(Wn2[D * NDIM + n]);
        }
        wn2f[kc] = mk_frag(u);
    }
    const float biasN0 = bn1p[w * 32 + l15];
    const float biasN1 = bn1p[w * 32 + 16 + l15];
    const float biasC0 = bc1p[w * 32 + l15];
    const float biasC1 = bc1p[w * 32 + 16 + l15];
    const float bias2v = bn2[w * 16 + l15];
    const float wcA = Wc2[w * 32 + l15];          // coord path: natural indexing
    const float wcB = Wc2[w * 32 + 16 + l15];

    // ---- prologue prefetch for first tile ----
    int psn[4], pdn[4];
    float4 phs[4], phd[4];
    float pdist;
    int psl = 0, pdl = 0;
    {
        const int e0 = blockIdx.x * 64;
#pragma unroll
        for (int it = 0; it < 4; ++it) {
            psn[it] = srcg[e0 + sub + it * 16];
            pdn[it] = dstg[e0 + sub + it * 16];
        }
#pragma unroll
        for (int it = 0; it < 4; ++it) {
            phs[it] = *(const float4*)(h + (size_t)psn[it] * NDIM + c4 * 4);
            phd[it] = *(const float4*)(h + (size_t)pdn[it] * NDIM + c4 * 4);
        }
        pdist = dist[e0 + (tid >> 2)];
        if (tid < 64) { psl = srcg[e0 + tid]; pdl = dstg[e0 + tid]; }
    }

    for (int tile = blockIdx.x; tile < NTILES; tile += gridDim.x) {
        bar_lds();   // (1) previous tile's LDS reads all done

        // ---- stage m_input from prefetched regs; issue epilogue x loads ----
        float xs0 = 0, xs1 = 0, xs2 = 0, xd0 = 0, xd1 = 0, xd2 = 0;
        if (tid < 64) {
            src_l[tid] = psl; dst_l[tid] = pdl;
            xs0 = x[psl * 3 + 0]; xs1 = x[psl * 3 + 1]; xs2 = x[psl * 3 + 2];
            xd0 = x[pdl * 3 + 0]; xd1 = x[pdl * 3 + 1]; xd2 = x[pdl * 3 + 2];
        }
#pragma unroll
        for (int it = 0; it < 4; ++it) {
            const int el = sub + it * 16;
            ushort4v us = { f2bf(phs[it].x), f2bf(phs[it].y), f2bf(phs[it].z), f2bf(phs[it].w) };
            ushort4v ud = { f2bf(phd[it].x), f2bf(phd[it].y), f2bf(phd[it].z), f2bf(phd[it].w) };
            *(ushort4v*)&mlds[el * MSTRIDE + c4 * 4] = us;
            *(ushort4v*)&mlds[el * MSTRIDE + 64 + c4 * 4] = ud;
        }
        {
            const int el = tid >> 2, j0 = (tid & 3) * 8;
            ushort8 u;
#pragma unroll
            for (int j = 0; j < 8; ++j)
                u[j] = f2bf(silu(pdist * we1_l[j0 + j] + be1_l[j0 + j]));
            *(ushort8*)&mlds[el * MSTRIDE + 128 + j0] = u;
        }
        bar_lds();   // (2) m_input ready

        // ---- prefetch next tile's indices (harmless reload of current on tail) ----
        {
            const int tn = tile + (int)gridDim.x;
            const int eb = (tn < NTILES ? tn : tile) * 64;
#pragma unroll
            for (int it = 0; it < 4; ++it) {
                psn[it] = srcg[eb + sub + it * 16];
                pdn[it] = dstg[eb + sub + it * 16];
            }
            pdist = dist[eb + (tid >> 2)];
            if (tid < 64) { psl = srcg[eb + tid]; pdl = dstg[eb + tid]; }
        }

        // ---- GEMM1 merged: [64x160] @ {Wn1', Wc1'} ----
        f32x4 accN[4][2], accC[4][2];
#pragma unroll
        for (int mt = 0; mt < 4; ++mt) {
            accN[mt][0] = (f32x4){biasN0, biasN0, biasN0, biasN0};
            accN[mt][1] = (f32x4){biasN1, biasN1, biasN1, biasN1};
            accC[mt][0] = (f32x4){biasC0, biasC0, biasC0, biasC0};
            accC[mt][1] = (f32x4){biasC1, biasC1, biasC1, biasC1};
        }
#pragma unroll
        for (int kc = 0; kc < 5; ++kc) {
            bf16x8 af[4];
#pragma unroll
            for (int mt = 0; mt < 4; ++mt)
                af[mt] = ld_frag(&mlds[(mt * 16 + l15) * MSTRIDE + kc * 32 + quad * 8]);
#pragma unroll
            for (int mt = 0; mt < 4; ++mt) {
#pragma unroll
                for (int nt = 0; nt < 2; ++nt) {
                    accN[mt][nt] = __builtin_amdgcn_mfma_f32_16x16x32_bf16(
                        af[mt], wn1f[kc][nt], accN[mt][nt], 0, 0, 0);
                    accC[mt][nt] = __builtin_amdgcn_mfma_f32_16x16x32_bf16(
                        af[mt], wc1f[kc][nt], accC[mt][nt], 0, 0, 0);
                }
            }
        }

        // ---- issue next tile's h gathers (land during GEMM2/epilogue) ----
#pragma unroll
        for (int it = 0; it < 4; ++it) {
            phs[it] = *(const float4*)(h + (size_t)psn[it] * NDIM + c4 * 4);
            phd[it] = *(const float4*)(h + (size_t)pdn[it] * NDIM + c4 * 4);
        }

        // ---- node path: silu -> hl, packed b32 writes (pi-permuted cols) ----
        {
            unsigned int* hlu = (unsigned int*)hl;
#pragma unroll
            for (int mt = 0; mt < 4; ++mt)
#pragma unroll
                for (int r = 0; r < 4; ++r) {
                    const unsigned int u0 = f2bf(silu(accN[mt][0][r]));
                    const unsigned int u1 = f2bf(silu(accN[mt][1][r]));
                    hlu[(mt * 16 + quad * 4 + r) * (HSTRIDE / 2) + w * 16 + l15] =
                        (u1 << 16) | u0;
                }
        }

        // ---- coord path: in-register silu*Wc2 + butterfly reduce over l15 ----
        {
            float p[16];
#pragma unroll
            for (int mt = 0; mt < 4; ++mt)
#pragma unroll
                for (int r = 0; r < 4; ++r)
                    p[mt * 4 + r] = silu(accC[mt][0][r]) * wcA + silu(accC[mt][1][r]) * wcB;

            float q8[8];
#pragma unroll
            for (int i = 0; i < 8; ++i) {
                const float send = (l15 & 8) ? p[i] : p[i + 8];
                const float recv = __shfl_xor(send, 8, 64);
                q8[i] = ((l15 & 8) ? p[i + 8] : p[i]) + recv;
            }
            float q4[4];
#pragma unroll
            for (int i = 0; i < 4; ++i) {
                const float send = (l15 & 4) ? q8[i] : q8[i + 4];
                const float recv = __shfl_xor(send, 4, 64);
                q4[i] = ((l15 & 4) ? q8[i + 4] : q8[i]) + recv;
            }
            float q2[2];
#pragma unroll
            for (int i = 0; i < 2; ++i) {
                const float send = (l15 & 2) ? q2[0] * 0.0f + ((l15 & 2) ? q4[i] : q4[i + 2]) : q4[i + 2];
                (void)send;
                const float s2 = (l15 & 2) ? q4[i] : q4[i + 2];
                const float recv = __shfl_xor(s2, 2, 64);
                q2[i] = ((l15 & 2) ? q4[i + 2] : q4[i]) + recv;
            }
            {
                const float send = (l15 & 1) ? q2[0] : q2[1];
                const float recv = __shfl_xor(send, 1, 64);
                const float tot = ((l15 & 1) ? q2[1] : q2[0]) + recv;
                const int edge = (l15 >> 2) * 16 + quad * 4 + (l15 & 3);
                part_l[w * 64 + edge] = tot;
            }
        }
        bar_lds();   // (3) hl + part_l ready

        // ---- GEMM2: [64x128] @ Wn2(pi) -> m [64x64], direct atomic scatter ----
        {
            f32x4 acc2[4];
#pragma unroll
            for (int mt = 0; mt < 4; ++mt) acc2[mt] = (f32x4){bias2v, bias2v, bias2v, bias2v};
#pragma unroll
            for (int kc = 0; kc < 4; ++kc) {
#pragma unroll
                for (int mt = 0; mt < 4; ++mt) {
                    bf16x8 a2 = ld_frag(&hl[(mt * 16 + l15) * HSTRIDE + kc * 32 + quad * 8]);
                    acc2[mt] = __builtin_amdgcn_mfma_f32_16x16x32_bf16(a2, wn2f[kc], acc2[mt], 0, 0, 0);
                }
            }
#pragma unroll
            for (int mt = 0; mt < 4; ++mt) {
#pragma unroll
                for (int r = 0; r < 4; ++r) {
                    const int el = mt * 16 + quad * 4 + r;
                    atomicAdd(outh + (size_t)dst_l[el] * NDIM + w * 16 + l15, acc2[mt][r]);
                }
            }
        }

        // ---- coord epilogue from prefetched x regs ----
        if (tid < 64) {
            const float cw = part_l[tid] + part_l[64 + tid] + part_l[128 + tid] + part_l[192 + tid];
            const float dx = xs0 - xd0;
            const float dy = xs1 - xd1;
            const float dz = xs2 - xd2;
            float len = sqrtf(dx * dx + dy * dy + dz * dz);
            len = fmaxf(len, 1e-8f);
            const float f = cw / len;
            const int dn = dst_l[tid];
            atomicAdd(outx + (size_t)dn * 3 + 0, f * dx);
            atomicAdd(outx + (size_t)dn * 3 + 1, f * dy);
            atomicAdd(outx + (size_t)dn * 3 + 2, f * dz);
        }
    }
}

extern "C" void kernel_launch(void* const* d_in, const int* in_sizes, int n_in,
                              void* d_out, int out_size, void* d_ws, size_t ws_size,
                              hipStream_t stream) {
    const float* h    = (const float*)d_in[0];
    const float* x    = (const float*)d_in[1];
    const int*   ei   = (const int*)d_in[2];     // int32, [2, NE]
    const float* dist = (const float*)d_in[3];
    const float* We1  = (const float*)d_in[4];
    const float* be1  = (const float*)d_in[5];
    const float* We2  = (const float*)d_in[6];
    const float* be2  = (const float*)d_in[7];
    const float* Wn1  = (const float*)d_in[8];
    const float* bn1  = (const float*)d_in[9];
    const float* Wn2  = (const float*)d_in[10];
    const float* bn2  = (const float*)d_in[11];
    const float* Wc1  = (const float*)d_in[12];
    const float* bc1  = (const float*)d_in[13];
    const float* Wc2  = (const float*)d_in[14];

    float* outh = (float*)d_out;
    float* outx = outh + (size_t)NH;
    float* ws   = (float*)d_ws;

    prep<<<2048, 256, 0, stream>>>(h, x, We2, be2, Wn1, bn1, Wc1, bc1,
                                   (float*)d_out, ws);
    egnn_edges<<<1024, 256, 0, stream>>>(h, x, ei, ei + NE, dist,
                                         We1, be1, Wn2, bn2, Wc2, ws,
                                         outh, outx);
}

// Round 7
// 416.519 us; speedup vs baseline: 1.4708x; 1.0677x over previous
//
#include <hip/hip_runtime.h>

// EGNN fused layer, MI355X gfx950 — v8 (v7 intent, deadlock-safe structure).
// out[0 : 50000*64)          = h + segment_sum(node messages, dst)
// out[50000*64 : +50000*3)   = x + segment_sum(coord updates, dst)
//
// v7 post-mortem: cooperative grid.sync deadlocked (loop body needs ~256
// regs/wave -> 1 block/CU -> 512 coop blocks can't co-reside -> hang).
// Never gate progress on a register estimate.  v8 = same optimizations,
// plain 2-launch structure (prep + main), no cooperative API.
// Changes vs v6 (last measured, 370us main at 1 blk/CU reg blowup):
//  - bf16 h table in d_ws (built in prep): halves gather bytes/lines,
//    deletes 16 staging cvts/thread, prefetch = 16 VGPRs not 32-64.
//    Register budget back under 2-blocks/CU (est ~130 arch + 64 acc).
//  - prep also folds We2/be2 into Wn1/Wc1 (ws) + inits out.  2 launches.
//  - keeps: pi-packed hl (16 ds_write_b32/thread), 3 lgkm-only barriers
//    per tile, direct atomic epilogue, index/dist/x prefetch.

#define NN 50000
#define NE 800000
#define NDIM 64
#define HDIM 128
#define NTILES (NE / 64)      // 12500, exact
#define MSTRIDE 168           // m_input LDS row stride (ushorts): 160 + 8 pad
#define HSTRIDE 136           // hidden LDS row stride (ushorts): 128 + 8 pad
#define NH (NN * NDIM)        // 3,200,000
#define NX (NN * 3)           // 150,000

// workspace layout
#define WS_WN1P 0             // [160][128] floats
#define WS_WC1P 20480         // [160][128] floats
#define WS_BN1P 40960         // [128]
#define WS_BC1P 41088         // [128]
#define WS_HBF_OFF 65536      // float offset -> hbf (ushort*), 256 KB in
#define WS_TOTAL_BYTES ((size_t)WS_HBF_OFF * 4 + (size_t)NH * 2)   // ~6.66 MB

typedef __bf16 bf16x8 __attribute__((ext_vector_type(8)));
typedef float f32x4 __attribute__((ext_vector_type(4)));
typedef unsigned short ushort8 __attribute__((ext_vector_type(8)));
typedef unsigned short ushort4v __attribute__((ext_vector_type(4)));

__device__ __forceinline__ unsigned short f2bf(float f) {
    union { __bf16 b; unsigned short u; } c;
    c.b = (__bf16)f;            // HW v_cvt (RNE)
    return c.u;
}
__device__ __forceinline__ float silu(float v) {
    return __fdividef(v, 1.0f + __expf(-v));
}
// lgkm-only barrier: all cross-thread deps flow through LDS; atomics and
// prefetch loads stay in flight across it.
__device__ __forceinline__ void bar_lds() {
    asm volatile("s_waitcnt lgkmcnt(0)" ::: "memory");
    __builtin_amdgcn_s_barrier();
}
__device__ __forceinline__ bf16x8 ld_frag(const unsigned short* p) {
    union { ushort8 u; bf16x8 v; } c;
    c.u = *(const ushort8*)p;
    return c.v;
}
__device__ __forceinline__ bf16x8 mk_frag(const unsigned short* u) {
    union { ushort8 uu; bf16x8 v; } c;
#pragma unroll
    for (int j = 0; j < 8; ++j) c.uu[j] = u[j];
    return c.v;
}

// ---- prep: fold weights -> ws, init out, build bf16 h table.  1 launch. ----
__global__ __launch_bounds__(256) void prep(
    const float* __restrict__ h, const float* __restrict__ x,
    const float* __restrict__ We2, const float* __restrict__ be2,
    const float* __restrict__ Wn1, const float* __restrict__ bn1,
    const float* __restrict__ Wc1, const float* __restrict__ bc1,
    float* __restrict__ out, float* __restrict__ wsf) {
    const int gtid = blockIdx.x * 256 + threadIdx.x;
    const int G = gridDim.x * 256;

    // fold We2/be2 into GEMM1 weights (first 41216 threads, one elem each)
    if (gtid < 41216) {
        if (gtid < 40960) {
            const int path = gtid / 20480;
            const int rem = gtid - path * 20480;
            const int r = rem >> 7, col = rem & 127;
            const float* W = path ? Wc1 : Wn1;
            float* Wp = wsf + (path ? WS_WC1P : WS_WN1P);
            if (r < 128) {
                Wp[r * 128 + col] = W[r * 128 + col];
            } else {
                const int j = r - 128;          // s-dim index 0..31
                float s = 0.0f;
#pragma unroll
                for (int n = 0; n < 32; ++n)
                    s += We2[j * 32 + n] * W[(128 + n) * 128 + col];
                Wp[r * 128 + col] = s;
            }
        } else {
            const int j = gtid - 40960;         // 0..255
            const int path = j >> 7, col = j & 127;
            const float* W = path ? Wc1 : Wn1;
            const float* bb = path ? bc1 : bn1;
            float s = bb[col];
#pragma unroll
            for (int n = 0; n < 32; ++n)
                s += be2[n] * W[(128 + n) * 128 + col];
            wsf[(path ? WS_BC1P : WS_BN1P) + col] = s;
        }
    }

    // init out[h] + build bf16 h table (vectorized), init out[x]
    unsigned short* hbf = (unsigned short*)(wsf + WS_HBF_OFF);
    const float4* h4 = (const float4*)h;
    float4* out4 = (float4*)out;
    for (int i = gtid; i < NH / 4; i += G) {
        const float4 v = h4[i];
        out4[i] = v;
        ushort4v u = { f2bf(v.x), f2bf(v.y), f2bf(v.z), f2bf(v.w) };
        *(ushort4v*)&hbf[i * 4] = u;
    }
    for (int i = gtid; i < NX; i += G) out[NH + i] = x[i];
}

// ---- main fused kernel ----
__global__ __launch_bounds__(256, 2) void egnn_edges(
    const float* __restrict__ x,
    const int* __restrict__ srcg, const int* __restrict__ dstg,
    const float* __restrict__ dist,
    const float* __restrict__ We1, const float* __restrict__ be1,
    const float* __restrict__ Wn2, const float* __restrict__ bn2,
    const float* __restrict__ Wc2,
    const float* __restrict__ wsW,
    float* __restrict__ outh, float* __restrict__ outx) {

    __shared__ __align__(16) unsigned short mlds[64 * MSTRIDE];  // m_input tile bf16
    __shared__ __align__(16) unsigned short hl[64 * HSTRIDE];    // hidden tile bf16 (pi-permuted)
    __shared__ int src_l[64];
    __shared__ int dst_l[64];
    __shared__ float we1_l[32], be1_l[32];
    __shared__ float part_l[256];

    const int tid  = threadIdx.x;
    const int w    = tid >> 6;        // wave 0..3
    const int lane = tid & 63;
    const int l15  = lane & 15;
    const int quad = lane >> 4;
    const int c4   = tid & 15, sub = tid >> 4;

    const unsigned short* hbf = (const unsigned short*)(wsW + WS_HBF_OFF);
    const float* Wn1p = wsW + WS_WN1P;
    const float* Wc1p = wsW + WS_WC1P;
    const float* bn1p = wsW + WS_BN1P;
    const float* bc1p = wsW + WS_BC1P;

    if (tid < 32) { we1_l[tid] = We1[tid]; be1_l[tid] = be1[tid]; }

    // ---- one-time: B-fragments from folded weights ----
    bf16x8 wn1f[5][2], wc1f[5][2];
#pragma unroll
    for (int kc = 0; kc < 5; ++kc) {
#pragma unroll
        for (int nt = 0; nt < 2; ++nt) {
            unsigned short un[8], uc[8];
            const int n = w * 32 + nt * 16 + l15;
#pragma unroll
            for (int j = 0; j < 8; ++j) {
                const int k = kc * 32 + quad * 8 + j;
                un[j] = f2bf(Wn1p[k * HDIM + n]);
                uc[j] = f2bf(Wc1p[k * HDIM + n]);
            }
            wn1f[kc][nt] = mk_frag(un);
            wc1f[kc][nt] = mk_frag(uc);
        }
    }
    // GEMM2 B-frags, pi-permuted k: slot k holds hidden dim
    // D(k) = (k&~31) + ((k&1)<<4) + ((k&31)>>1)   (matches hl packing below)
    bf16x8 wn2f[4];
#pragma unroll
    for (int kc = 0; kc < 4; ++kc) {
        unsigned short u[8];
        const int n = w * 16 + l15;
#pragma unroll
        for (int j = 0; j < 8; ++j) {
            const int k = kc * 32 + quad * 8 + j;
            const int D = (k & ~31) + ((k & 1) << 4) + ((k & 31) >> 1);
            u[j] = f2bf(Wn2[D * NDIM + n]);
        }
        wn2f[kc] = mk_frag(u);
    }
    const float biasN0 = bn1p[w * 32 + l15];
    const float biasN1 = bn1p[w * 32 + 16 + l15];
    const float biasC0 = bc1p[w * 32 + l15];
    const float biasC1 = bc1p[w * 32 + 16 + l15];
    const float bias2v = bn2[w * 16 + l15];
    const float wcA = Wc2[w * 32 + l15];
    const float wcB = Wc2[w * 32 + 16 + l15];

    // ---- prologue prefetch for first tile ----
    int psn[4], pdn[4];
    float pdist;
    int psl = 0, pdl = 0;
    ushort4v pus[4], pud[4];
    {
        const int e0 = blockIdx.x * 64;
#pragma unroll
        for (int it = 0; it < 4; ++it) {
            psn[it] = srcg[e0 + sub + it * 16];
            pdn[it] = dstg[e0 + sub + it * 16];
        }
        pdist = dist[e0 + (tid >> 2)];
        if (tid < 64) { psl = srcg[e0 + tid]; pdl = dstg[e0 + tid]; }
#pragma unroll
        for (int it = 0; it < 4; ++it) {
            pus[it] = *(const ushort4v*)(hbf + (size_t)psn[it] * NDIM + c4 * 4);
            pud[it] = *(const ushort4v*)(hbf + (size_t)pdn[it] * NDIM + c4 * 4);
        }
    }

    for (int tile = blockIdx.x; tile < NTILES; tile += gridDim.x) {
        bar_lds();   // (1) previous tile's LDS reads all done

        // ---- stage m_input from prefetched bf16 regs; issue epilogue x loads ----
        float xs0 = 0, xs1 = 0, xs2 = 0, xd0 = 0, xd1 = 0, xd2 = 0;
        if (tid < 64) {
            src_l[tid] = psl; dst_l[tid] = pdl;
            xs0 = x[psl * 3 + 0]; xs1 = x[psl * 3 + 1]; xs2 = x[psl * 3 + 2];
            xd0 = x[pdl * 3 + 0]; xd1 = x[pdl * 3 + 1]; xd2 = x[pdl * 3 + 2];
        }
#pragma unroll
        for (int it = 0; it < 4; ++it) {
            const int el = sub + it * 16;
            *(ushort4v*)&mlds[el * MSTRIDE + c4 * 4] = pus[it];
            *(ushort4v*)&mlds[el * MSTRIDE + 64 + c4 * 4] = pud[it];
        }
        {
            const int el = tid >> 2, j0 = (tid & 3) * 8;
            ushort8 u;
#pragma unroll
            for (int j = 0; j < 8; ++j)
                u[j] = f2bf(silu(pdist * we1_l[j0 + j] + be1_l[j0 + j]));
            *(ushort8*)&mlds[el * MSTRIDE + 128 + j0] = u;
        }
        bar_lds();   // (2) m_input ready

        // ---- prefetch next tile's indices (lands under GEMM1) ----
        {
            const int tn = tile + (int)gridDim.x;
            const int eb = (tn < NTILES ? tn : tile) * 64;
#pragma unroll
            for (int it = 0; it < 4; ++it) {
                psn[it] = srcg[eb + sub + it * 16];
                pdn[it] = dstg[eb + sub + it * 16];
            }
            pdist = dist[eb + (tid >> 2)];
            if (tid < 64) { psl = srcg[eb + tid]; pdl = dstg[eb + tid]; }
        }

        // ---- GEMM1 merged: [64x160] @ {Wn1', Wc1'} ----
        f32x4 accN[4][2], accC[4][2];
#pragma unroll
        for (int mt = 0; mt < 4; ++mt) {
            accN[mt][0] = (f32x4){biasN0, biasN0, biasN0, biasN0};
            accN[mt][1] = (f32x4){biasN1, biasN1, biasN1, biasN1};
            accC[mt][0] = (f32x4){biasC0, biasC0, biasC0, biasC0};
            accC[mt][1] = (f32x4){biasC1, biasC1, biasC1, biasC1};
        }
#pragma unroll
        for (int kc = 0; kc < 5; ++kc) {
            bf16x8 af[4];
#pragma unroll
            for (int mt = 0; mt < 4; ++mt)
                af[mt] = ld_frag(&mlds[(mt * 16 + l15) * MSTRIDE + kc * 32 + quad * 8]);
#pragma unroll
            for (int mt = 0; mt < 4; ++mt) {
#pragma unroll
                for (int nt = 0; nt < 2; ++nt) {
                    accN[mt][nt] = __builtin_amdgcn_mfma_f32_16x16x32_bf16(
                        af[mt], wn1f[kc][nt], accN[mt][nt], 0, 0, 0);
                    accC[mt][nt] = __builtin_amdgcn_mfma_f32_16x16x32_bf16(
                        af[mt], wc1f[kc][nt], accC[mt][nt], 0, 0, 0);
                }
            }
        }

        // ---- issue next tile's bf16 row gathers (land during GEMM2/epilogue) ----
#pragma unroll
        for (int it = 0; it < 4; ++it) {
            pus[it] = *(const ushort4v*)(hbf + (size_t)psn[it] * NDIM + c4 * 4);
            pud[it] = *(const ushort4v*)(hbf + (size_t)pdn[it] * NDIM + c4 * 4);
        }

        // ---- node path: silu -> hl, packed b32 writes (pi-permuted cols) ----
        {
            unsigned int* hlu = (unsigned int*)hl;
#pragma unroll
            for (int mt = 0; mt < 4; ++mt)
#pragma unroll
                for (int r = 0; r < 4; ++r) {
                    const unsigned int u0 = f2bf(silu(accN[mt][0][r]));
                    const unsigned int u1 = f2bf(silu(accN[mt][1][r]));
                    hlu[(mt * 16 + quad * 4 + r) * (HSTRIDE / 2) + w * 16 + l15] =
                        (u1 << 16) | u0;
                }
        }

        // ---- coord path: in-register silu*Wc2 + butterfly reduce over l15 ----
        {
            float p[16];
#pragma unroll
            for (int mt = 0; mt < 4; ++mt)
#pragma unroll
                for (int r = 0; r < 4; ++r)
                    p[mt * 4 + r] = silu(accC[mt][0][r]) * wcA + silu(accC[mt][1][r]) * wcB;

            float q8[8];
#pragma unroll
            for (int i = 0; i < 8; ++i) {
                const float send = (l15 & 8) ? p[i] : p[i + 8];
                const float recv = __shfl_xor(send, 8, 64);
                q8[i] = ((l15 & 8) ? p[i + 8] : p[i]) + recv;
            }
            float q4[4];
#pragma unroll
            for (int i = 0; i < 4; ++i) {
                const float send = (l15 & 4) ? q8[i] : q8[i + 4];
                const float recv = __shfl_xor(send, 4, 64);
                q4[i] = ((l15 & 4) ? q8[i + 4] : q8[i]) + recv;
            }
            float q2[2];
#pragma unroll
            for (int i = 0; i < 2; ++i) {
                const float send = (l15 & 2) ? q4[i] : q4[i + 2];
                const float recv = __shfl_xor(send, 2, 64);
                q2[i] = ((l15 & 2) ? q4[i + 2] : q4[i]) + recv;
            }
            {
                const float send = (l15 & 1) ? q2[0] : q2[1];
                const float recv = __shfl_xor(send, 1, 64);
                const float tot = ((l15 & 1) ? q2[1] : q2[0]) + recv;
                const int edge = (l15 >> 2) * 16 + quad * 4 + (l15 & 3);
                part_l[w * 64 + edge] = tot;
            }
        }
        bar_lds();   // (3) hl + part_l ready

        // ---- GEMM2: [64x128] @ Wn2(pi) -> m [64x64], direct atomic scatter ----
        {
            f32x4 acc2[4];
#pragma unroll
            for (int mt = 0; mt < 4; ++mt) acc2[mt] = (f32x4){bias2v, bias2v, bias2v, bias2v};
#pragma unroll
            for (int kc = 0; kc < 4; ++kc) {
#pragma unroll
                for (int mt = 0; mt < 4; ++mt) {
                    bf16x8 a2 = ld_frag(&hl[(mt * 16 + l15) * HSTRIDE + kc * 32 + quad * 8]);
                    acc2[mt] = __builtin_amdgcn_mfma_f32_16x16x32_bf16(a2, wn2f[kc], acc2[mt], 0, 0, 0);
                }
            }
#pragma unroll
            for (int mt = 0; mt < 4; ++mt) {
#pragma unroll
                for (int r = 0; r < 4; ++r) {
                    const int el = mt * 16 + quad * 4 + r;
                    atomicAdd(outh + (size_t)dst_l[el] * NDIM + w * 16 + l15, acc2[mt][r]);
                }
            }
        }

        // ---- coord epilogue from prefetched x regs ----
        if (tid < 64) {
            const float cw = part_l[tid] + part_l[64 + tid] + part_l[128 + tid] + part_l[192 + tid];
            const float dx = xs0 - xd0;
            const float dy = xs1 - xd1;
            const float dz = xs2 - xd2;
            float len = sqrtf(dx * dx + dy * dy + dz * dz);
            len = fmaxf(len, 1e-8f);
            const float f = cw / len;
            const int dn = dst_l[tid];
            atomicAdd(outx + (size_t)dn * 3 + 0, f * dx);
            atomicAdd(outx + (size_t)dn * 3 + 1, f * dy);
            atomicAdd(outx + (size_t)dn * 3 + 2, f * dz);
        }
    }
}

extern "C" void kernel_launch(void* const* d_in, const int* in_sizes, int n_in,
                              void* d_out, int out_size, void* d_ws, size_t ws_size,
                              hipStream_t stream) {
    const float* h    = (const float*)d_in[0];
    const float* x    = (const float*)d_in[1];
    const int*   ei   = (const int*)d_in[2];     // int32, [2, NE]
    const float* dist = (const float*)d_in[3];
    const float* We1  = (const float*)d_in[4];
    const float* be1  = (const float*)d_in[5];
    const float* We2  = (const float*)d_in[6];
    const float* be2  = (const float*)d_in[7];
    const float* Wn1  = (const float*)d_in[8];
    const float* bn1  = (const float*)d_in[9];
    const float* Wn2  = (const float*)d_in[10];
    const float* bn2  = (const float*)d_in[11];
    const float* Wc1  = (const float*)d_in[12];
    const float* bc1  = (const float*)d_in[13];
    const float* Wc2  = (const float*)d_in[14];

    float* out = (float*)d_out;
    float* ws  = (float*)d_ws;                   // ws_size >= 10.3 MB (proven in v4)

    prep<<<2048, 256, 0, stream>>>(h, x, We2, be2, Wn1, bn1, Wc1, bc1, out, ws);
    egnn_edges<<<1024, 256, 0, stream>>>(x, ei, ei + NE, dist,
                                         We1, be1, Wn2, bn2, Wc2, ws,
                                         out, out + NH);
}